// Round 2
// baseline (2452.899 us; speedup 1.0000x reference)
//
#include <hip/hip_runtime.h>
#include <hip/hip_bf16.h>
#include <math.h>

#define M_  4
#define N_  50000
#define E_  400000
#define IN_ 128
#define C_  128
#define HID_ 256

// ---------------------------------------------------------------------------
// Tiled f32 GEMM, 128 rows x COLS (full output width) per block, 8x8 micro.
// threads = 2*COLS (256 or 512). Block covers ALL columns -> A fetched once.
// AMODE 0: A[r*K+k]
// AMODE 1: A[r*K+k] - A2[r*K+k]                  (feat_diff = out1 - xd)
// AMODE 2: A[(k>>7)*strideM + r*128 + (k&127)]   (gate_in view of feats[M,N,C])
// AMODE 3: A[idx[r]*K + k]                       (gathered rows)
// EPI 0: store   1: relu-store   2: sigmoid-store
// EPI 4: final[idx[r]*128 + c] += rowscale[idx[r]] * (acc + bias[c])
// Reff = cntp ? *cntp : R  (device-side row count for compacted launches)
// ---------------------------------------------------------------------------
template<int AMODE, int EPI, int COLS>
__global__ void __launch_bounds__(2 * COLS) gemm2(
    const float* __restrict__ A, const float* __restrict__ A2,
    const float* __restrict__ B, const float* __restrict__ bias,
    float* __restrict__ Cmat, const float* __restrict__ rowscale,
    const int* __restrict__ idx, const int* __restrict__ cntp,
    int R, int K, long long strideM)
{
  __shared__ float As[8][128];
  __shared__ float Bs[8][COLS];

  const int tid = threadIdx.x;
  const int Reff = cntp ? cntp[0] : R;
  const int rb = blockIdx.x * 128;
  if (rb >= Reff) return;

  const int tx = tid % (COLS / 8);
  const int ty = tid / (COLS / 8);          // 0..15

  // A loader (first 256 threads): 128 rows x 8 k, one float4 each
  const int ar = tid >> 1;                  // 0..127
  const int ak = (tid & 1) * 4;             // 0 or 4
  const int r_a = rb + ar;
  const bool a_valid = (tid < 256) && (r_a < Reff);
  long long abase = 0;
  if (a_valid) {
    if (AMODE == 3)      abase = (long long)idx[r_a] * K;
    else if (AMODE == 2) abase = (long long)r_a * 128;
    else                 abase = (long long)r_a * K;
  }

  // B loader: 8 k x COLS, one float4 each (all threads)
  const int bk = tid / (COLS / 4);
  const int bc = (tid % (COLS / 4)) * 4;

  float acc[8][8];
  #pragma unroll
  for (int i = 0; i < 8; ++i)
    #pragma unroll
    for (int j = 0; j < 8; ++j) acc[i][j] = 0.f;

  for (int k0 = 0; k0 < K; k0 += 8) {
    if (tid < 256) {
      float4 av = make_float4(0.f, 0.f, 0.f, 0.f);
      if (a_valid) {
        if (AMODE == 0 || AMODE == 3) {
          av = *(const float4*)(A + abase + k0 + ak);
        } else if (AMODE == 1) {
          float4 x1 = *(const float4*)(A  + abase + k0 + ak);
          float4 x2 = *(const float4*)(A2 + abase + k0 + ak);
          av = make_float4(x1.x - x2.x, x1.y - x2.y, x1.z - x2.z, x1.w - x2.w);
        } else { // AMODE 2
          int kk0 = k0 + ak;
          av = *(const float4*)(A + (long long)(kk0 >> 7) * strideM + abase + (kk0 & 127));
        }
      }
      As[ak + 0][ar] = av.x;
      As[ak + 1][ar] = av.y;
      As[ak + 2][ar] = av.z;
      As[ak + 3][ar] = av.w;
    }
    {
      float4 bv = *(const float4*)(B + (long long)(k0 + bk) * COLS + bc);
      *(float4*)(&Bs[bk][bc]) = bv;
    }
    __syncthreads();
    #pragma unroll
    for (int kk = 0; kk < 8; ++kk) {
      float4 a0 = *(float4*)(&As[kk][ty * 8]);
      float4 a1 = *(float4*)(&As[kk][ty * 8 + 4]);
      float4 b0 = *(float4*)(&Bs[kk][tx * 8]);
      float4 b1 = *(float4*)(&Bs[kk][tx * 8 + 4]);
      float av[8] = {a0.x, a0.y, a0.z, a0.w, a1.x, a1.y, a1.z, a1.w};
      float bv[8] = {b0.x, b0.y, b0.z, b0.w, b1.x, b1.y, b1.z, b1.w};
      #pragma unroll
      for (int i = 0; i < 8; ++i)
        #pragma unroll
        for (int j = 0; j < 8; ++j)
          acc[i][j] += av[i] * bv[j];
    }
    __syncthreads();
  }

  #pragma unroll
  for (int i = 0; i < 8; ++i) {
    int r = rb + ty * 8 + i;
    if (r >= Reff) continue;
    int orow = 0; float w = 0.f;
    if (EPI == 4) { orow = idx[r]; w = rowscale[orow]; }
    #pragma unroll
    for (int j = 0; j < 8; ++j) {
      int c = tx * 8 + j;
      float v = acc[i][j] + bias[c];
      if (EPI == 1) v = fmaxf(v, 0.f);
      if (EPI == 2) v = 1.f / (1.f + expf(-v));
      if (EPI == 4) Cmat[(long long)orow * 128 + c] += w * v;
      else          Cmat[(long long)r * COLS + c] = v;
    }
  }
}

// a[m*Nn + n] = dot(X[row(n)], lin[m*128 ..])  ; perM: row = m*Nn+n else n
__global__ void attn_logit_kernel(const float* __restrict__ X, const float* __restrict__ lin,
                                  float* __restrict__ out, int Nn, int perM)
{
  int m = blockIdx.y;
  int w = blockIdx.x * (blockDim.x >> 6) + (threadIdx.x >> 6);
  int lane = threadIdx.x & 63;
  if (w >= Nn) return;
  long long row = perM ? ((long long)m * Nn + w) : (long long)w;
  const float* xr = X + row * 128;
  const float* lr = lin + m * 128;
  float acc = xr[lane] * lr[lane] + xr[lane + 64] * lr[lane + 64];
  #pragma unroll
  for (int off = 32; off > 0; off >>= 1) acc += __shfl_down(acc, off);
  if (lane == 0) out[(long long)m * Nn + w] = acc;
}

// ---- CSR build ----
__global__ void count_kernel(const int* __restrict__ dst, int* __restrict__ cnt, int Nn)
{
  int e = blockIdx.x * blockDim.x + threadIdx.x;
  int m = blockIdx.y;
  if (e >= E_) return;
  atomicAdd(&cnt[(long long)m * Nn + dst[(long long)m * E_ + e]], 1);
}

__global__ void scan_kernel(const int* __restrict__ cnt, int* __restrict__ rowptr, int Nn)
{
  __shared__ int sd[1024];
  int m = blockIdx.x;
  int tid = threadIdx.x;
  const int* c = cnt + (long long)m * Nn;
  int* rp = rowptr + (long long)m * (Nn + 1);
  if (tid == 0) rp[0] = 0;
  int running = 0;
  for (int base = 0; base < Nn; base += 1024) {
    int i = base + tid;
    int v = (i < Nn) ? c[i] : 0;
    sd[tid] = v;
    __syncthreads();
    for (int off = 1; off < 1024; off <<= 1) {
      int t = (tid >= off) ? sd[tid - off] : 0;
      __syncthreads();
      sd[tid] += t;
      __syncthreads();
    }
    if (i < Nn) rp[i + 1] = running + sd[tid];
    int tot = sd[1023];
    __syncthreads();
    running += tot;
  }
}

__global__ void scatter_kernel(const int* __restrict__ dst, const int* __restrict__ rowptr,
                               int* __restrict__ fill, int* __restrict__ col, int Nn)
{
  int e = blockIdx.x * blockDim.x + threadIdx.x;
  int m = blockIdx.y;
  if (e >= E_) return;
  int d = dst[(long long)m * E_ + e];
  int pos = rowptr[(long long)m * (Nn + 1) + d] + atomicAdd(&fill[(long long)m * Nn + d], 1);
  col[(long long)m * E_ + pos] = e;   // store edge id
}

// per-bucket insertion sort by edge id -> deterministic, np edge order
__global__ void sortbucket_kernel(const int* __restrict__ rowptr, int* __restrict__ col, int Nn)
{
  int n = blockIdx.x * blockDim.x + threadIdx.x;
  int m = blockIdx.y;
  if (n >= Nn) return;
  const int* rp = rowptr + (long long)m * (Nn + 1);
  int* c = col + (long long)m * E_;
  int b = rp[n], e = rp[n + 1];
  for (int i = b + 1; i < e; ++i) {
    int v = c[i]; int j = i - 1;
    while (j >= b && c[j] > v) { c[j + 1] = c[j]; --j; }
    c[j + 1] = v;
  }
}

// fused GAT propagation for one edge type (gather, no atomics)
__global__ void prop_kernel(const float* __restrict__ xsm, const float* __restrict__ asrcm,
                            const float* __restrict__ adstm, const int* __restrict__ rp,
                            const int* __restrict__ colm, const int* __restrict__ srcm,
                            const float* __restrict__ receptm, float* __restrict__ outm,
                            int do_relu)
{
  int d = blockIdx.x;
  int c = threadIdx.x;   // 128
  int b = rp[d], en = rp[d + 1];
  long long obase = (long long)d * 128 + c;
  if (b == en) { outm[obase] = 0.f; return; }
  float ad = adstm[d];
  float emax = -INFINITY;
  for (int j = b; j < en; ++j) {
    int s = srcm[colm[j]];
    float e = asrcm[s] + ad;
    e = (e >= 0.f) ? e : 0.2f * e;
    emax = fmaxf(emax, e);
  }
  float den = 0.f, acc = 0.f;
  for (int j = b; j < en; ++j) {
    int s = srcm[colm[j]];
    float e = asrcm[s] + ad;
    e = (e >= 0.f) ? e : 0.2f * e;
    float ez = expf(e - emax);
    den += ez;
    acc += ez * xsm[(long long)s * 128 + c];
  }
  float r = receptm ? receptm[d] : 1.f;
  float v = acc * (r / (den + 1e-16f));
  if (do_relu) v = fmaxf(v, 0.f);
  outm[obase] = v;
}

// gd = mean_c(mo * (out1 - xd)); recept = gd/(|gd|+1e-8)
__global__ void gd_kernel(const float* __restrict__ mo, const float* __restrict__ out1,
                          const float* __restrict__ xd, float* __restrict__ recept)
{
  int n = blockIdx.x;
  int c = threadIdx.x;  // 128
  long long idx = (long long)n * 128 + c;
  float fd = out1[idx] - xd[idx];
  float v = mo[idx] * fd;
  __shared__ float red[128];
  red[c] = v;
  __syncthreads();
  for (int off = 64; off > 0; off >>= 1) {
    if (c < off) red[c] += red[c + off];
    __syncthreads();
  }
  if (c == 0) {
    float gd = red[0] / 128.f;
    recept[n] = gd / (fabsf(gd) + 1e-8f);
  }
}

// logits[n, 0..3] = h[n,0..255] @ W2[256,4] + b2
__global__ void gate_logits_kernel(const float* __restrict__ h, const float* __restrict__ W2,
                                   const float* __restrict__ b2, float* __restrict__ logits, int Nn)
{
  int w = blockIdx.x * (blockDim.x >> 6) + (threadIdx.x >> 6);
  int lane = threadIdx.x & 63;
  if (w >= Nn) return;
  const float* hr = h + (long long)w * 256;
  float a0 = 0.f, a1 = 0.f, a2 = 0.f, a3 = 0.f;
  for (int j = lane; j < 256; j += 64) {
    float hv = hr[j];
    a0 += hv * W2[j * 4 + 0];
    a1 += hv * W2[j * 4 + 1];
    a2 += hv * W2[j * 4 + 2];
    a3 += hv * W2[j * 4 + 3];
  }
  #pragma unroll
  for (int off = 32; off > 0; off >>= 1) {
    a0 += __shfl_down(a0, off);
    a1 += __shfl_down(a1, off);
    a2 += __shfl_down(a2, off);
    a3 += __shfl_down(a3, off);
  }
  if (lane == 0) {
    long long o = (long long)w * 4;
    logits[o + 0] = a0 + b2[0];
    logits[o + 1] = a1 + b2[1];
    logits[o + 2] = a2 + b2[2];
    logits[o + 3] = a3 + b2[3];
  }
}

// softmax + recept.T + top-2 (jax tie rule: lower index first) -> wsel[M,N]
__global__ void topk_kernel(const float* __restrict__ logits, const float* __restrict__ recept,
                            float* __restrict__ wsel, int Nn)
{
  int n = blockIdx.x * blockDim.x + threadIdx.x;
  if (n >= Nn) return;
  float l[4];
  #pragma unroll
  for (int m = 0; m < 4; ++m) l[m] = logits[(long long)n * 4 + m];
  float mx = fmaxf(fmaxf(l[0], l[1]), fmaxf(l[2], l[3]));
  float e[4], s = 0.f;
  #pragma unroll
  for (int m = 0; m < 4; ++m) { e[m] = expf(l[m] - mx); s += e[m]; }
  float sc[4];
  #pragma unroll
  for (int m = 0; m < 4; ++m) sc[m] = e[m] / s + recept[(long long)m * Nn + n];
  int i0 = 0; float v0 = sc[0];
  #pragma unroll
  for (int m = 1; m < 4; ++m) if (sc[m] > v0) { v0 = sc[m]; i0 = m; }
  int i1 = -1; float v1 = -INFINITY;
  #pragma unroll
  for (int m = 0; m < 4; ++m) { if (m == i0) continue; if (sc[m] > v1) { v1 = sc[m]; i1 = m; } }
  float ts = v0 + v1;
  float w0 = v0 / ts, w1 = v1 / ts;
  #pragma unroll
  for (int m = 0; m < 4; ++m)
    wsel[(long long)m * Nn + n] = (m == i0) ? w0 : ((m == i1) ? w1 : 0.f);
}

// build per-expert selected-row lists (order-independent result)
__global__ void compact_kernel(const float* __restrict__ wsel, int* __restrict__ idx,
                               int* __restrict__ cnts, int Nn)
{
  int n = blockIdx.x * blockDim.x + threadIdx.x;
  if (n >= Nn) return;
  #pragma unroll
  for (int m = 0; m < 4; ++m) {
    if (wsel[(long long)m * Nn + n] != 0.f) {
      int p = atomicAdd(&cnts[m], 1);
      idx[(long long)m * Nn + p] = n;
    }
  }
}

extern "C" void kernel_launch(void* const* d_in, const int* in_sizes, int n_in,
                              void* d_out, int out_size, void* d_ws, size_t ws_size,
                              hipStream_t stream) {
  const float* x_src   = (const float*)d_in[0];
  const float* x_dst   = (const float*)d_in[1];
  const int*   src_idx = (const int*)d_in[2];
  const int*   dst_idx = (const int*)d_in[3];
  const float* proj_Ws = (const float*)d_in[4];
  const float* proj_bs = (const float*)d_in[5];
  const float* projd_W = (const float*)d_in[6];
  const float* projd_b = (const float*)d_in[7];
  const float* lin_src = (const float*)d_in[8];
  const float* lin_dst = (const float*)d_in[9];
  const float* gm_W1   = (const float*)d_in[10];
  const float* gm_b1   = (const float*)d_in[11];
  const float* gm_W2   = (const float*)d_in[12];
  const float* gm_b2   = (const float*)d_in[13];
  const float* gate_W1 = (const float*)d_in[14];
  const float* gate_b1 = (const float*)d_in[15];
  const float* gate_W2 = (const float*)d_in[16];
  const float* gate_b2 = (const float*)d_in[17];
  const float* exp_W1  = (const float*)d_in[18];
  const float* exp_b1  = (const float*)d_in[19];
  const float* exp_W2  = (const float*)d_in[20];
  const float* exp_b2  = (const float*)d_in[21];
  float* final_out = (float*)d_out;

  float* ws = (float*)d_ws;
  float* xs     = ws;                        // [M,N,C]
  float* feats  = ws + 25600000LL;           // [M,N,C] (out1 -> out2/feats)
  float* xd     = ws + 51200000LL;           // [N,C]
  float* tbuf   = ws + 57600000LL;           // [N,HID]
  float* mo     = tbuf + 6400000LL;          // [N,C] overlay in tbuf upper half
  float* asrc   = ws + 70400000LL;           // [M,N]
  float* adst   = ws + 70600000LL;           // [M,N]
  float* recept = ws + 70800000LL;           // [M,N]
  float* wsel   = ws + 71000000LL;           // [M,N]
  float* logits = ws + 71200000LL;           // [N,4]
  int*   ibase  = (int*)(ws + 71400000LL);
  int*   rowptr = ibase;                     // [M,(N+1)]
  int*   col    = ibase + 200004;            // [M,E]  (expcnt reuses this after pass2)
  int*   cnt    = ibase + 1800004;           // [M,N]  (expidx reuses this after pass2)
  int*   expidx = cnt;                       // [M,N] reuse (CSR build done by then)
  int*   expcnt = col;                       // [4] reuse (props done by then)

  const long long NC = (long long)N_ * C_;
  const int RB = (N_ + 127) / 128;           // 391 row blocks

  hipMemsetAsync(d_out, 0, (size_t)out_size * sizeof(float), stream);

  // ---- CSR build (all m) ----
  hipMemsetAsync(cnt, 0, (size_t)M_ * N_ * sizeof(int), stream);
  count_kernel<<<dim3((E_ + 255) / 256, M_), 256, 0, stream>>>(dst_idx, cnt, N_);
  scan_kernel<<<M_, 1024, 0, stream>>>(cnt, rowptr, N_);
  hipMemsetAsync(cnt, 0, (size_t)M_ * N_ * sizeof(int), stream);
  scatter_kernel<<<dim3((E_ + 255) / 256, M_), 256, 0, stream>>>(dst_idx, rowptr, cnt, col, N_);
  sortbucket_kernel<<<dim3((N_ + 255) / 256, M_), 256, 0, stream>>>(rowptr, col, N_);

  // ---- xd = x_dst @ projd_W + b ----
  gemm2<0, 0, 128><<<RB, 256, 0, stream>>>(x_dst, nullptr, projd_W, projd_b, xd,
                                           nullptr, nullptr, nullptr, N_, IN_, 0);
  attn_logit_kernel<<<dim3((N_ + 3) / 4, M_), 256, 0, stream>>>(xd, lin_dst, adst, N_, 0);

  // ---- per-type projection + a_src ----
  for (int m = 0; m < M_; ++m) {
    gemm2<0, 0, 128><<<RB, 256, 0, stream>>>(x_src + (long long)m * N_ * IN_, nullptr,
                                             proj_Ws + (long long)m * IN_ * C_,
                                             proj_bs + (long long)m * C_,
                                             xs + m * NC, nullptr, nullptr, nullptr,
                                             N_, IN_, 0);
  }
  attn_logit_kernel<<<dim3((N_ + 3) / 4, M_), 256, 0, stream>>>(xs, lin_src, asrc, N_, 1);

  // ---- pass 1: out1 (stored in feats) ----
  for (int m = 0; m < M_; ++m) {
    prop_kernel<<<N_, 128, 0, stream>>>(xs + m * NC, asrc + (long long)m * N_,
                                        adst + (long long)m * N_,
                                        rowptr + (long long)m * (N_ + 1),
                                        col + (long long)m * E_,
                                        src_idx + (long long)m * E_,
                                        nullptr, feats + m * NC, 0);
  }

  // ---- grad-map MLP -> recept ----
  for (int m = 0; m < M_; ++m) {
    gemm2<1, 1, 128><<<RB, 256, 0, stream>>>(feats + m * NC, xd, gm_W1, gm_b1,
                                             tbuf, nullptr, nullptr, nullptr, N_, C_, 0);
    gemm2<0, 2, 128><<<RB, 256, 0, stream>>>(tbuf, nullptr, gm_W2, gm_b2,
                                             mo, nullptr, nullptr, nullptr, N_, C_, 0);
    gd_kernel<<<N_, 128, 0, stream>>>(mo, feats + m * NC, xd, recept + (long long)m * N_);
  }

  // ---- pass 2: out2 -> relu -> feats ----
  for (int m = 0; m < M_; ++m) {
    prop_kernel<<<N_, 128, 0, stream>>>(xs + m * NC, asrc + (long long)m * N_,
                                        adst + (long long)m * N_,
                                        rowptr + (long long)m * (N_ + 1),
                                        col + (long long)m * E_,
                                        src_idx + (long long)m * E_,
                                        recept + (long long)m * N_, feats + m * NC, 1);
  }

  // ---- gate: hidden = relu(gate_in @ W1 + b1), gate_in strided view of feats ----
  gemm2<2, 1, 256><<<RB, 512, 0, stream>>>(feats, nullptr, gate_W1, gate_b1,
                                           tbuf, nullptr, nullptr, nullptr,
                                           N_, M_ * C_, NC);
  gate_logits_kernel<<<dim3((N_ + 3) / 4), 256, 0, stream>>>(tbuf, gate_W2, gate_b2, logits, N_);
  topk_kernel<<<(N_ + 255) / 256, 256, 0, stream>>>(logits, recept, wsel, N_);

  // ---- top-2 compaction ----
  hipMemsetAsync(expcnt, 0, 4 * sizeof(int), stream);
  compact_kernel<<<(N_ + 255) / 256, 256, 0, stream>>>(wsel, expidx, expcnt, N_);

  // ---- experts (compacted rows only, weighted scatter-accumulate into final) ----
  for (int m = 0; m < M_; ++m) {
    gemm2<3, 1, 256><<<RB, 512, 0, stream>>>(feats + m * NC, nullptr,
                                             exp_W1 + (long long)m * C_ * HID_,
                                             exp_b1 + (long long)m * HID_,
                                             tbuf, nullptr,
                                             expidx + (long long)m * N_, expcnt + m,
                                             N_, C_, 0);
    gemm2<0, 4, 128><<<RB, 256, 0, stream>>>(tbuf, nullptr,
                                             exp_W2 + (long long)m * HID_ * C_,
                                             exp_b2 + (long long)m * C_,
                                             final_out, wsel + (long long)m * N_,
                                             expidx + (long long)m * N_, expcnt + m,
                                             N_, HID_, 0);
  }
}